// Round 5
// baseline (140.327 us; speedup 1.0000x reference)
//
#include <hip/hip_runtime.h>
#include <math.h>

constexpr int B_ = 8, C_ = 1280, H_ = 7, W_ = 7;
constexpr int M_ = 2048, N_ = 128, HID = 256, NC = 21;
constexpr int DET_OFF = M_ * NC;          // 43008
constexpr int IOU_OFF = M_ * NC + M_ * 4; // 51200

typedef __attribute__((ext_vector_type(8))) short bf16x8;
typedef __attribute__((ext_vector_type(8))) unsigned short u16x8;
typedef __attribute__((ext_vector_type(4))) float f32x4;

// ws layout (bytes)
constexpr size_t W1T_OFF = 0;                      // 1280*256*2 = 655360
constexpr size_t W2T_OFF = W1T_OFF + 655360;       // 256*256*2  = 131072
constexpr size_t WHT_OFF = W2T_OFF + 131072;       // 32*256*2   =  16384
constexpr size_t FMT_OFF = WHT_OFF + 16384;        // 8*49*1280*4 = 2007040

// k_aux grid partitions
constexpr int TR_BLKS      = B_ * 20;   // (img, 64-ch tile) = 160
constexpr int PREP_W1_BLKS = 160;       // 1280*256 / (256*8)
constexpr int PREP_W2_BLKS = 32;
constexpr int PREP_WH_BLKS = 4;
constexpr int AUX_BLKS = TR_BLKS + PREP_W1_BLKS + PREP_W2_BLKS + PREP_WH_BLKS; // 356

__device__ __forceinline__ unsigned short f2bf(float f) {
    unsigned u = __builtin_bit_cast(unsigned, f);
    u += 0x7FFFu + ((u >> 16) & 1u);   // round-to-nearest-even
    return (unsigned short)(u >> 16);
}

__device__ __forceinline__ float4 max4(float4 a, float4 b) {
    return make_float4(fmaxf(a.x, b.x), fmaxf(a.y, b.y),
                       fmaxf(a.z, b.z), fmaxf(a.w, b.w));
}

// ---------- fused: fmap transpose ([B][C][49] -> [B][49][C]) + weight prep ----------
__global__ __launch_bounds__(256) void k_aux(
    const float* __restrict__ fmap,
    const float* __restrict__ W1, const float* __restrict__ W2,
    const float* __restrict__ Wc, const float* __restrict__ Wd,
    float* __restrict__ fmt, unsigned short* __restrict__ W1t,
    unsigned short* __restrict__ W2t, unsigned short* __restrict__ Wht)
{
    const int tid = threadIdx.x;
    const int b = blockIdx.x;

    if (b < TR_BLKS) {
        __shared__ float tile[64 * 49];   // 12.25 KB
        int img = b / 20, c0 = (b % 20) * 64;
        const float* src = fmap + ((size_t)img * C_ + c0) * 49;
        for (int i4 = tid; i4 < 784; i4 += 256)
            *(float4*)&tile[i4 * 4] = *(const float4*)(src + i4 * 4);
        __syncthreads();
        float* dst = fmt + (size_t)img * 49 * C_ + c0;
        for (int w4 = tid; w4 < 784; w4 += 256) {
            int px = w4 >> 4, j = w4 & 15;
            float4 v = make_float4(tile[(4 * j + 0) * 49 + px],
                                   tile[(4 * j + 1) * 49 + px],
                                   tile[(4 * j + 2) * 49 + px],
                                   tile[(4 * j + 3) * 49 + px]);
            *(float4*)(dst + (size_t)px * C_ + 4 * j) = v;
        }
    } else if (b < TR_BLKS + PREP_W1_BLKS) {
        int k0 = (b - TR_BLKS) * 8;
        int col = tid;
        u16x8 o;
        #pragma unroll
        for (int j = 0; j < 8; ++j) o[j] = f2bf(W1[(size_t)(k0 + j) * HID + col]);
        *(u16x8*)(W1t + (size_t)col * C_ + k0) = o;
    } else if (b < TR_BLKS + PREP_W1_BLKS + PREP_W2_BLKS) {
        int k0 = (b - TR_BLKS - PREP_W1_BLKS) * 8;
        int col = tid;
        u16x8 o;
        #pragma unroll
        for (int j = 0; j < 8; ++j) o[j] = f2bf(W2[(size_t)(k0 + j) * HID + col]);
        *(u16x8*)(W2t + (size_t)col * HID + k0) = o;
    } else {
        int i = (b - TR_BLKS - PREP_W1_BLKS - PREP_W2_BLKS) * 256 + tid;
        int o32 = i & 31;
        int k0  = (i >> 5) * 8;
        u16x8 o;
        #pragma unroll
        for (int j = 0; j < 8; ++j) {
            float v = 0.0f;
            if (o32 < NC) v = Wc[(size_t)(k0 + j) * NC + o32];
            else if (o32 < NC + 4) v = Wd[(size_t)(k0 + j) * 4 + (o32 - NC)];
            o[j] = f2bf(v);
        }
        *(u16x8*)(Wht + (size_t)o32 * HID + k0) = o;
    }
}

// ---------- fused pool -> FC1 -> FC2 -> heads + IoU; 8 proposals/block ----------
__global__ __launch_bounds__(256) void k_fc(
    const float* __restrict__ fmt,
    const unsigned short* __restrict__ W1t,
    const unsigned short* __restrict__ W2t,
    const unsigned short* __restrict__ Wht,
    const float* __restrict__ b1v, const float* __restrict__ b2v,
    const float* __restrict__ bc,  const float* __restrict__ bd,
    const float* __restrict__ props, const int* __restrict__ pbid,
    const float* __restrict__ bbx,   const int* __restrict__ gbid,
    float* __restrict__ out)
{
    __shared__ unsigned short featL[8][1288];   // 20.6 KB, pitch 1288 (bank-spread)
    __shared__ unsigned short h1s[16][264];
    __shared__ unsigned short h2s[16][264];
    __shared__ float gbox[N_][4];
    __shared__ int   gids[N_];

    const int tid = threadIdx.x;
    const int w = tid >> 6, lane = tid & 63;
    const int r = lane & 15, g = lane >> 4;
    const int row0 = blockIdx.x * 8;
    const int col0 = w * 64;

    for (int i = tid; i < N_; i += 256) {
        gbox[i][0] = bbx[i * 5 + 0];
        gbox[i][1] = bbx[i * 5 + 1];
        gbox[i][2] = bbx[i * 5 + 2];
        gbox[i][3] = bbx[i * 5 + 3];
        gids[i] = gbid[i];
    }

    // ---- pool: thread = (proposal p, 4-ch column), 10 column groups ----
    {
        const int p  = tid >> 5;       // 0..7
        const int cl = tid & 31;       // 32 lanes x 4ch = 128-ch stripe
        const int m  = row0 + p;
        float4 bx = *(const float4*)(props + (size_t)m * 4);
        float x1 = rintf(bx.x), y1 = rintf(bx.y);
        float x2 = rintf(bx.z), y2 = rintf(bx.w);
        float rw = fmaxf(x2 - x1 + 1.0f, 1.0f);
        float rh = fmaxf(y2 - y1 + 1.0f, 1.0f);
        float bw = rw * 0.5f, bh = rh * 0.5f;
        int hs0 = (int)fminf(fmaxf(y1, 0.f), 7.f);
        int he0 = (int)fminf(fmaxf(ceilf(bh) + y1, 0.f), 7.f);
        int hs1 = (int)fminf(fmaxf(floorf(bh) + y1, 0.f), 7.f);
        int he1 = (int)fminf(fmaxf(ceilf(2.f * bh) + y1, 0.f), 7.f);
        int ws0 = (int)fminf(fmaxf(x1, 0.f), 7.f);
        int we0 = (int)fminf(fmaxf(ceilf(bw) + x1, 0.f), 7.f);
        int ws1 = (int)fminf(fmaxf(floorf(bw) + x1, 0.f), 7.f);
        int we1 = (int)fminf(fmaxf(ceilf(2.f * bw) + x1, 0.f), 7.f);
        bool e00 = (he0 <= hs0) | (we0 <= ws0);
        bool e01 = (he0 <= hs0) | (we1 <= ws1);
        bool e10 = (he1 <= hs1) | (we0 <= ws0);
        bool e11 = (he1 <= hs1) | (we1 <= ws1);
        int bid = pbid[m];

        const float* base = fmt + (size_t)bid * 49 * C_ + cl * 4;
        const float4 ninf = make_float4(-INFINITY, -INFINITY, -INFINITY, -INFINITY);
        const float4 z    = make_float4(0.f, 0.f, 0.f, 0.f);

        for (int j = 0; j < 10; ++j) {
            const float* bj = base + j * 128;
            float4 b00 = ninf, b01 = ninf, b10 = ninf, b11 = ninf;
            for (int y = hs0; y < he1; ++y) {
                float4 r0 = ninf, r1 = ninf;
                const float* rp = bj + (y * 7) * C_;
                for (int x = ws0; x < we1; ++x) {
                    float4 v = *(const float4*)(rp + x * C_);
                    if (x < we0)  r0 = max4(r0, v);
                    if (x >= ws1) r1 = max4(r1, v);
                }
                if (y < he0)  { b00 = max4(b00, r0); b01 = max4(b01, r1); }
                if (y >= hs1) { b10 = max4(b10, r0); b11 = max4(b11, r1); }
            }
            float4 f00 = e00 ? z : b00;
            float4 f01 = e01 ? z : b01;
            float4 f10 = e10 ? z : b10;
            float4 f11 = e11 ? z : b11;
            ushort4 o;
            o.x = f2bf((f00.x + f01.x + f10.x + f11.x) * 0.25f);
            o.y = f2bf((f00.y + f01.y + f10.y + f11.y) * 0.25f);
            o.z = f2bf((f00.z + f01.z + f10.z + f11.z) * 0.25f);
            o.w = f2bf((f00.w + f01.w + f10.w + f11.w) * 0.25f);
            *(ushort4*)&featL[p][cl * 4 + j * 128] = o;
        }
    }
    __syncthreads();

    // ---- FC1: A from LDS (rows 8..15 duplicate 0..7) ----
    f32x4 acc[4];
    #pragma unroll
    for (int f = 0; f < 4; ++f) acc[f] = (f32x4){0.f, 0.f, 0.f, 0.f};

    const unsigned short* bp = W1t + (size_t)(col0 + r) * C_ + g * 8;
    for (int ks = 0; ks < C_ / 32; ++ks) {
        bf16x8 a = *(const bf16x8*)&featL[r & 7][ks * 32 + g * 8];
        #pragma unroll
        for (int f = 0; f < 4; ++f) {
            bf16x8 b = *(const bf16x8*)(bp + (size_t)f * 16 * C_ + ks * 32);
            acc[f] = __builtin_amdgcn_mfma_f32_16x16x32_bf16(a, b, acc[f], 0, 0, 0);
        }
    }
    #pragma unroll
    for (int f = 0; f < 4; ++f) {
        int col = col0 + f * 16 + r;
        float bias = b1v[col];
        #pragma unroll
        for (int i = 0; i < 4; ++i)
            h1s[g * 4 + i][col] = f2bf(fmaxf(acc[f][i] + bias, 0.f));
    }
    __syncthreads();

    // ---- FC2 ----
    f32x4 acc2[4];
    #pragma unroll
    for (int f = 0; f < 4; ++f) acc2[f] = (f32x4){0.f, 0.f, 0.f, 0.f};

    const unsigned short* bp2 = W2t + (size_t)(col0 + r) * HID + g * 8;
    for (int ks = 0; ks < HID / 32; ++ks) {
        bf16x8 a = *(const bf16x8*)(&h1s[r][ks * 32 + g * 8]);
        #pragma unroll
        for (int f = 0; f < 4; ++f) {
            bf16x8 b = *(const bf16x8*)(bp2 + (size_t)f * 16 * HID + ks * 32);
            acc2[f] = __builtin_amdgcn_mfma_f32_16x16x32_bf16(a, b, acc2[f], 0, 0, 0);
        }
    }
    #pragma unroll
    for (int f = 0; f < 4; ++f) {
        int col = col0 + f * 16 + r;
        float bias = b2v[col];
        #pragma unroll
        for (int i = 0; i < 4; ++i)
            h2s[g * 4 + i][col] = f2bf(acc2[f][i] + bias);
    }
    __syncthreads();

    // ---- heads on wave 0: rows 0..7 valid ----
    if (w == 0) {
        f32x4 acc3[2];
        #pragma unroll
        for (int f = 0; f < 2; ++f) acc3[f] = (f32x4){0.f, 0.f, 0.f, 0.f};
        const unsigned short* bp3 = Wht + (size_t)r * HID + g * 8;
        for (int ks = 0; ks < HID / 32; ++ks) {
            bf16x8 a = *(const bf16x8*)(&h2s[r][ks * 32 + g * 8]);
            #pragma unroll
            for (int f = 0; f < 2; ++f) {
                bf16x8 b = *(const bf16x8*)(bp3 + (size_t)f * 16 * HID + ks * 32);
                acc3[f] = __builtin_amdgcn_mfma_f32_16x16x32_bf16(a, b, acc3[f], 0, 0, 0);
            }
        }
        if (g < 2) {
            #pragma unroll
            for (int f = 0; f < 2; ++f) {
                int col = f * 16 + r;
                #pragma unroll
                for (int i = 0; i < 4; ++i) {
                    int m = row0 + g * 4 + i;
                    if (col < NC)
                        out[(size_t)m * NC + col] = acc3[f][i] + bc[col];
                    else if (col < NC + 4)
                        out[DET_OFF + (size_t)m * 4 + (col - NC)] = acc3[f][i] + bd[col - NC];
                }
            }
        }
    }

    // ---- IoU: 32 threads per proposal ----
    {
        int rr = tid >> 5, l = tid & 31;
        int m = row0 + rr;
        float4 bx = *(const float4*)(props + (size_t)m * 4);
        float ap2 = (bx.z - bx.x) * (bx.w - bx.y);
        int pb = pbid[m];
        float best = 0.0f;
        for (int n = l; n < N_; n += 32) {
            if (gids[n] == pb) {
                float ix = fmaxf(fminf(bx.z, gbox[n][2]) - fmaxf(bx.x, gbox[n][0]), 0.0f);
                float iy = fmaxf(fminf(bx.w, gbox[n][3]) - fmaxf(bx.y, gbox[n][1]), 0.0f);
                float inter = ix * iy;
                float ag = (gbox[n][2] - gbox[n][0]) * (gbox[n][3] - gbox[n][1]);
                float un = fmaxf(ap2 + ag - inter, 1e-6f);
                best = fmaxf(best, inter / un);
            }
        }
        #pragma unroll
        for (int off = 16; off; off >>= 1)
            best = fmaxf(best, __shfl_xor(best, off));
        if (l == 0) out[IOU_OFF + m] = best;
    }
}

extern "C" void kernel_launch(void* const* d_in, const int* in_sizes, int n_in,
                              void* d_out, int out_size, void* d_ws, size_t ws_size,
                              hipStream_t stream) {
    const float* fmap  = (const float*)d_in[0];
    const float* props = (const float*)d_in[1];
    const float* bbx   = (const float*)d_in[2];
    const float* W1    = (const float*)d_in[3];
    const float* b1v   = (const float*)d_in[4];
    const float* W2    = (const float*)d_in[5];
    const float* b2v   = (const float*)d_in[6];
    const float* Wc    = (const float*)d_in[7];
    const float* bc    = (const float*)d_in[8];
    const float* Wd    = (const float*)d_in[9];
    const float* bd    = (const float*)d_in[10];
    const int*   pbid  = (const int*)d_in[11];
    const int*   gbid  = (const int*)d_in[12];
    float* out = (float*)d_out;

    char* ws = (char*)d_ws;
    unsigned short* W1t = (unsigned short*)(ws + W1T_OFF);
    unsigned short* W2t = (unsigned short*)(ws + W2T_OFF);
    unsigned short* Wht = (unsigned short*)(ws + WHT_OFF);
    float*          fmt = (float*)(ws + FMT_OFF);

    k_aux<<<dim3(AUX_BLKS), dim3(256), 0, stream>>>(
        fmap, W1, W2, Wc, Wd, fmt, W1t, W2t, Wht);
    k_fc<<<dim3(M_ / 8), dim3(256), 0, stream>>>(
        fmt, W1t, W2t, Wht, b1v, b2v, bc, bd, props, pbid, bbx, gbid, out);
}

// Round 6
// 63.231 us; speedup vs baseline: 2.2193x; 2.2193x over previous
//
#include <hip/hip_runtime.h>
#include <math.h>

constexpr int B_ = 8, C_ = 1280, H_ = 7, W_ = 7;
constexpr int M_ = 2048, N_ = 128, HID = 256, NC = 21;
constexpr int DET_OFF = M_ * NC;          // 43008
constexpr int IOU_OFF = M_ * NC + M_ * 4; // 51200

typedef __attribute__((ext_vector_type(8))) short bf16x8;
typedef __attribute__((ext_vector_type(8))) unsigned short u16x8;
typedef __attribute__((ext_vector_type(4))) float f32x4;

// ws layout (bytes)
constexpr size_t W1T_OFF   = 0;                    // 1280*256*2 = 655360
constexpr size_t W2T_OFF   = W1T_OFF + 655360;     // 256*256*2  = 131072
constexpr size_t WHT_OFF   = W2T_OFF + 131072;     // 32*256*2   =  16384
constexpr size_t FMT_OFF   = WHT_OFF + 16384;      // 8*49*1280*4 = 2007040
constexpr size_t FEATB_OFF = FMT_OFF + 2007040;    // 2048*1280*2 = 5242880

// k_aux grid partitions
constexpr int TR_BLKS      = B_ * 20;   // (img, 64-ch tile) = 160
constexpr int PREP_W1_BLKS = 160;       // 1280*256 / (256*8)
constexpr int PREP_W2_BLKS = 32;
constexpr int PREP_WH_BLKS = 4;
constexpr int AUX_BLKS = TR_BLKS + PREP_W1_BLKS + PREP_W2_BLKS + PREP_WH_BLKS; // 356

__device__ __forceinline__ unsigned short f2bf(float f) {
    unsigned u = __builtin_bit_cast(unsigned, f);
    u += 0x7FFFu + ((u >> 16) & 1u);   // round-to-nearest-even
    return (unsigned short)(u >> 16);
}

__device__ __forceinline__ float4 max4(float4 a, float4 b) {
    return make_float4(fmaxf(a.x, b.x), fmaxf(a.y, b.y),
                       fmaxf(a.z, b.z), fmaxf(a.w, b.w));
}

// ---------- fused: fmap transpose ([B][C][49] -> [B][49][C]) + weight prep ----------
__global__ __launch_bounds__(256) void k_aux(
    const float* __restrict__ fmap,
    const float* __restrict__ W1, const float* __restrict__ W2,
    const float* __restrict__ Wc, const float* __restrict__ Wd,
    float* __restrict__ fmt, unsigned short* __restrict__ W1t,
    unsigned short* __restrict__ W2t, unsigned short* __restrict__ Wht)
{
    const int tid = threadIdx.x;
    const int b = blockIdx.x;

    if (b < TR_BLKS) {
        __shared__ float tile[64 * 49];   // 12.25 KB
        int img = b / 20, c0 = (b % 20) * 64;
        const float* src = fmap + ((size_t)img * C_ + c0) * 49;
        for (int i4 = tid; i4 < 784; i4 += 256)
            *(float4*)&tile[i4 * 4] = *(const float4*)(src + i4 * 4);
        __syncthreads();
        float* dst = fmt + (size_t)img * 49 * C_ + c0;
        for (int w4 = tid; w4 < 784; w4 += 256) {
            int px = w4 >> 4, j = w4 & 15;
            float4 v = make_float4(tile[(4 * j + 0) * 49 + px],
                                   tile[(4 * j + 1) * 49 + px],
                                   tile[(4 * j + 2) * 49 + px],
                                   tile[(4 * j + 3) * 49 + px]);
            *(float4*)(dst + (size_t)px * C_ + 4 * j) = v;
        }
    } else if (b < TR_BLKS + PREP_W1_BLKS) {
        int k0 = (b - TR_BLKS) * 8;
        int col = tid;
        u16x8 o;
        #pragma unroll
        for (int j = 0; j < 8; ++j) o[j] = f2bf(W1[(size_t)(k0 + j) * HID + col]);
        *(u16x8*)(W1t + (size_t)col * C_ + k0) = o;
    } else if (b < TR_BLKS + PREP_W1_BLKS + PREP_W2_BLKS) {
        int k0 = (b - TR_BLKS - PREP_W1_BLKS) * 8;
        int col = tid;
        u16x8 o;
        #pragma unroll
        for (int j = 0; j < 8; ++j) o[j] = f2bf(W2[(size_t)(k0 + j) * HID + col]);
        *(u16x8*)(W2t + (size_t)col * HID + k0) = o;
    } else {
        int i = (b - TR_BLKS - PREP_W1_BLKS - PREP_W2_BLKS) * 256 + tid;
        int o32 = i & 31;
        int k0  = (i >> 5) * 8;
        u16x8 o;
        #pragma unroll
        for (int j = 0; j < 8; ++j) {
            float v = 0.0f;
            if (o32 < NC) v = Wc[(size_t)(k0 + j) * NC + o32];
            else if (o32 < NC + 4) v = Wd[(size_t)(k0 + j) * 4 + (o32 - NC)];
            o[j] = f2bf(v);
        }
        *(u16x8*)(Wht + (size_t)o32 * HID + k0) = o;
    }
}

// ---------- ROI pool: wave = (proposal, 256-ch slab); scalar bounds, unrolled x ----------
__global__ __launch_bounds__(256) void k_pool(
    const float* __restrict__ fmt, const float* __restrict__ props,
    const int* __restrict__ pbid, unsigned short* __restrict__ featb)
{
    int wg   = blockIdx.x * 4 + (threadIdx.x >> 6);   // 10240 waves
    int lane = threadIdx.x & 63;
    int m    = wg / 5;
    int slab = wg - m * 5;
    int c0   = slab * 256 + lane * 4;

    float4 bx = *(const float4*)(props + (size_t)m * 4);
    float x1 = rintf(bx.x), y1 = rintf(bx.y);
    float x2 = rintf(bx.z), y2 = rintf(bx.w);
    float rw = fmaxf(x2 - x1 + 1.0f, 1.0f);
    float rh = fmaxf(y2 - y1 + 1.0f, 1.0f);
    float bw = rw * 0.5f, bh = rh * 0.5f;
    // force all bounds to SGPRs: wave-uniform scalar branches below
    int hs0 = __builtin_amdgcn_readfirstlane((int)fminf(fmaxf(y1, 0.f), 7.f));
    int he0 = __builtin_amdgcn_readfirstlane((int)fminf(fmaxf(ceilf(bh) + y1, 0.f), 7.f));
    int hs1 = __builtin_amdgcn_readfirstlane((int)fminf(fmaxf(floorf(bh) + y1, 0.f), 7.f));
    int he1 = __builtin_amdgcn_readfirstlane((int)fminf(fmaxf(ceilf(2.f * bh) + y1, 0.f), 7.f));
    int ws0 = __builtin_amdgcn_readfirstlane((int)fminf(fmaxf(x1, 0.f), 7.f));
    int we0 = __builtin_amdgcn_readfirstlane((int)fminf(fmaxf(ceilf(bw) + x1, 0.f), 7.f));
    int ws1 = __builtin_amdgcn_readfirstlane((int)fminf(fmaxf(floorf(bw) + x1, 0.f), 7.f));
    int we1 = __builtin_amdgcn_readfirstlane((int)fminf(fmaxf(ceilf(2.f * bw) + x1, 0.f), 7.f));
    int bid = __builtin_amdgcn_readfirstlane(pbid[m]);

    const float* base = fmt + ((size_t)bid * 49) * C_ + c0;
    const float4 ninf = make_float4(-INFINITY, -INFINITY, -INFINITY, -INFINITY);
    float4 b00 = ninf, b01 = ninf, b10 = ninf, b11 = ninf;

    for (int y = hs0; y < he1; ++y) {
        const float* rp = base + (y * 7) * C_;
        float4 v[7];
        #pragma unroll
        for (int x = 0; x < 7; ++x) v[x] = *(const float4*)(rp + x * C_);
        float4 r0 = ninf, r1 = ninf;
        #pragma unroll
        for (int x = 0; x < 7; ++x) {
            if (x >= ws0 && x < we0) r0 = max4(r0, v[x]);
            if (x >= ws1 && x < we1) r1 = max4(r1, v[x]);
        }
        if (y < he0)  { b00 = max4(b00, r0); b01 = max4(b01, r1); }
        if (y >= hs1) { b10 = max4(b10, r0); b11 = max4(b11, r1); }
    }

    bool e00 = (he0 <= hs0) | (we0 <= ws0);
    bool e01 = (he0 <= hs0) | (we1 <= ws1);
    bool e10 = (he1 <= hs1) | (we0 <= ws0);
    bool e11 = (he1 <= hs1) | (we1 <= ws1);
    float4 z = make_float4(0.f, 0.f, 0.f, 0.f);
    float4 f00 = e00 ? z : b00;
    float4 f01 = e01 ? z : b01;
    float4 f10 = e10 ? z : b10;
    float4 f11 = e11 ? z : b11;

    ushort4 o;
    o.x = f2bf((f00.x + f01.x + f10.x + f11.x) * 0.25f);
    o.y = f2bf((f00.y + f01.y + f10.y + f11.y) * 0.25f);
    o.z = f2bf((f00.z + f01.z + f10.z + f11.z) * 0.25f);
    o.w = f2bf((f00.w + f01.w + f10.w + f11.w) * 0.25f);
    *(ushort4*)(featb + (size_t)m * C_ + c0) = o;
}

// ---------- fused FC1 -> FC2 -> heads + IoU; 8 proposals/block, 8 waves ----------
__global__ __launch_bounds__(512) void k_fc(
    const unsigned short* __restrict__ featb,
    const unsigned short* __restrict__ W1t,
    const unsigned short* __restrict__ W2t,
    const unsigned short* __restrict__ Wht,
    const float* __restrict__ b1v, const float* __restrict__ b2v,
    const float* __restrict__ bc,  const float* __restrict__ bd,
    const float* __restrict__ props, const int* __restrict__ pbid,
    const float* __restrict__ bbx,   const int* __restrict__ gbid,
    float* __restrict__ out)
{
    __shared__ unsigned short h1s[16][264];
    __shared__ unsigned short h2s[16][264];
    __shared__ float gbox[N_][4];
    __shared__ int   gids[N_];

    const int tid = threadIdx.x;
    const int w = tid >> 6, lane = tid & 63;
    const int r = lane & 15, g = lane >> 4;
    const int row0 = blockIdx.x * 8;          // 8 valid rows; MFMA rows 8..15 duplicate
    const int arow = row0 + (r & 7);
    const int col0 = w * 32;                  // wave covers 32 cols (2 MFMA quadrants)

    if (tid < N_) {
        gbox[tid][0] = bbx[tid * 5 + 0];
        gbox[tid][1] = bbx[tid * 5 + 1];
        gbox[tid][2] = bbx[tid * 5 + 2];
        gbox[tid][3] = bbx[tid * 5 + 3];
        gids[tid] = gbid[tid];
    }

    // ---- FC1: prefetched K-loop ----
    f32x4 acc0 = (f32x4){0.f, 0.f, 0.f, 0.f};
    f32x4 acc1 = (f32x4){0.f, 0.f, 0.f, 0.f};
    const unsigned short* ap  = featb + (size_t)arow * C_ + g * 8;
    const unsigned short* bp0 = W1t + (size_t)(col0 + r) * C_ + g * 8;
    const unsigned short* bp1 = bp0 + 16 * C_;

    bf16x8 a_c  = *(const bf16x8*)ap;
    bf16x8 b0_c = *(const bf16x8*)bp0;
    bf16x8 b1_c = *(const bf16x8*)bp1;
    for (int ks = 1; ks < 40; ++ks) {
        bf16x8 a_n  = *(const bf16x8*)(ap  + ks * 32);
        bf16x8 b0_n = *(const bf16x8*)(bp0 + ks * 32);
        bf16x8 b1_n = *(const bf16x8*)(bp1 + ks * 32);
        acc0 = __builtin_amdgcn_mfma_f32_16x16x32_bf16(a_c, b0_c, acc0, 0, 0, 0);
        acc1 = __builtin_amdgcn_mfma_f32_16x16x32_bf16(a_c, b1_c, acc1, 0, 0, 0);
        a_c = a_n; b0_c = b0_n; b1_c = b1_n;
    }
    acc0 = __builtin_amdgcn_mfma_f32_16x16x32_bf16(a_c, b0_c, acc0, 0, 0, 0);
    acc1 = __builtin_amdgcn_mfma_f32_16x16x32_bf16(a_c, b1_c, acc1, 0, 0, 0);

    {
        int colA = col0 + r, colB = col0 + 16 + r;
        float biasA = b1v[colA], biasB = b1v[colB];
        #pragma unroll
        for (int i = 0; i < 4; ++i) {
            h1s[g * 4 + i][colA] = f2bf(fmaxf(acc0[i] + biasA, 0.f));
            h1s[g * 4 + i][colB] = f2bf(fmaxf(acc1[i] + biasB, 0.f));
        }
    }
    __syncthreads();

    // ---- FC2 ----
    f32x4 c0v = (f32x4){0.f, 0.f, 0.f, 0.f};
    f32x4 c1v = (f32x4){0.f, 0.f, 0.f, 0.f};
    const unsigned short* bq0 = W2t + (size_t)(col0 + r) * HID + g * 8;
    const unsigned short* bq1 = bq0 + 16 * HID;
    #pragma unroll
    for (int ks = 0; ks < 8; ++ks) {
        bf16x8 a  = *(const bf16x8*)(&h1s[r][ks * 32 + g * 8]);
        bf16x8 u0 = *(const bf16x8*)(bq0 + ks * 32);
        bf16x8 u1 = *(const bf16x8*)(bq1 + ks * 32);
        c0v = __builtin_amdgcn_mfma_f32_16x16x32_bf16(a, u0, c0v, 0, 0, 0);
        c1v = __builtin_amdgcn_mfma_f32_16x16x32_bf16(a, u1, c1v, 0, 0, 0);
    }
    {
        int colA = col0 + r, colB = col0 + 16 + r;
        float biasA = b2v[colA], biasB = b2v[colB];
        #pragma unroll
        for (int i = 0; i < 4; ++i) {
            h2s[g * 4 + i][colA] = f2bf(c0v[i] + biasA);
            h2s[g * 4 + i][colB] = f2bf(c1v[i] + biasB);
        }
    }
    __syncthreads();

    // ---- heads on wave 0: 32 cols (21 cls + 4 det + pad), rows 0..7 valid ----
    if (w == 0) {
        f32x4 acc3[2];
        #pragma unroll
        for (int f = 0; f < 2; ++f) acc3[f] = (f32x4){0.f, 0.f, 0.f, 0.f};
        const unsigned short* bp3 = Wht + (size_t)r * HID + g * 8;
        #pragma unroll
        for (int ks = 0; ks < 8; ++ks) {
            bf16x8 a = *(const bf16x8*)(&h2s[r][ks * 32 + g * 8]);
            #pragma unroll
            for (int f = 0; f < 2; ++f) {
                bf16x8 b = *(const bf16x8*)(bp3 + (size_t)f * 16 * HID + ks * 32);
                acc3[f] = __builtin_amdgcn_mfma_f32_16x16x32_bf16(a, b, acc3[f], 0, 0, 0);
            }
        }
        if (g < 2) {
            #pragma unroll
            for (int f = 0; f < 2; ++f) {
                int col = f * 16 + r;
                #pragma unroll
                for (int i = 0; i < 4; ++i) {
                    int m = row0 + g * 4 + i;
                    if (col < NC)
                        out[(size_t)m * NC + col] = acc3[f][i] + bc[col];
                    else if (col < NC + 4)
                        out[DET_OFF + (size_t)m * 4 + (col - NC)] = acc3[f][i] + bd[col - NC];
                }
            }
        }
    }

    // ---- IoU: wave w handles proposal row0+w ----
    {
        int m = row0 + w;
        float4 bxp = *(const float4*)(props + (size_t)m * 4);
        float ap2 = (bxp.z - bxp.x) * (bxp.w - bxp.y);
        int pb = pbid[m];
        float best = 0.0f;
        for (int n = lane; n < N_; n += 64) {
            if (gids[n] == pb) {
                float ix = fmaxf(fminf(bxp.z, gbox[n][2]) - fmaxf(bxp.x, gbox[n][0]), 0.0f);
                float iy = fmaxf(fminf(bxp.w, gbox[n][3]) - fmaxf(bxp.y, gbox[n][1]), 0.0f);
                float inter = ix * iy;
                float ag = (gbox[n][2] - gbox[n][0]) * (gbox[n][3] - gbox[n][1]);
                float un = fmaxf(ap2 + ag - inter, 1e-6f);
                best = fmaxf(best, inter / un);
            }
        }
        #pragma unroll
        for (int off = 32; off; off >>= 1)
            best = fmaxf(best, __shfl_xor(best, off));
        if (lane == 0) out[IOU_OFF + m] = best;
    }
}

extern "C" void kernel_launch(void* const* d_in, const int* in_sizes, int n_in,
                              void* d_out, int out_size, void* d_ws, size_t ws_size,
                              hipStream_t stream) {
    const float* fmap  = (const float*)d_in[0];
    const float* props = (const float*)d_in[1];
    const float* bbx   = (const float*)d_in[2];
    const float* W1    = (const float*)d_in[3];
    const float* b1v   = (const float*)d_in[4];
    const float* W2    = (const float*)d_in[5];
    const float* b2v   = (const float*)d_in[6];
    const float* Wc    = (const float*)d_in[7];
    const float* bc    = (const float*)d_in[8];
    const float* Wd    = (const float*)d_in[9];
    const float* bd    = (const float*)d_in[10];
    const int*   pbid  = (const int*)d_in[11];
    const int*   gbid  = (const int*)d_in[12];
    float* out = (float*)d_out;

    char* ws = (char*)d_ws;
    unsigned short* W1t   = (unsigned short*)(ws + W1T_OFF);
    unsigned short* W2t   = (unsigned short*)(ws + W2T_OFF);
    unsigned short* Wht   = (unsigned short*)(ws + WHT_OFF);
    float*          fmt   = (float*)(ws + FMT_OFF);
    unsigned short* featb = (unsigned short*)(ws + FEATB_OFF);

    k_aux<<<dim3(AUX_BLKS), dim3(256), 0, stream>>>(
        fmap, W1, W2, Wc, Wd, fmt, W1t, W2t, Wht);
    k_pool<<<dim3(M_ * 5 / 4), dim3(256), 0, stream>>>(fmt, props, pbid, featb);
    k_fc<<<dim3(M_ / 8), dim3(512), 0, stream>>>(
        featb, W1t, W2t, Wht, b1v, b2v, bc, bd, props, pbid, bbx, gbid, out);
}